// Round 1
// baseline (201.043 us; speedup 1.0000x reference)
//
#include <hip/hip_runtime.h>

// PCE basis expansion: Phi[n,b] = prod_j polyval(xn[n,j], idxset[b,j])
// D=50, P=2 -> each idxset row has <= 2 nonzero orders; polyval(_,0) == 1.
// So Phi[n,b] = pv[dim0*3+ord0] * pv[dim1*3+ord1] with a 150-entry per-row
// polyval table. Output 32768x1326 fp32 = 174 MB -> write-BW bound (~28 us floor).

#define DD     50
#define P1     3
#define NBASIS 1326
#define BN     8
#define BLOCK  256

// Kernel A: compress idxset rows into packed LDS-offset descriptors.
__global__ void build_desc_kernel(const int* __restrict__ idxset,
                                  int* __restrict__ desc, int nbasis, int d) {
    int b = blockIdx.x * blockDim.x + threadIdx.x;
    if (b >= nbasis) return;
    const int* row = idxset + (size_t)b * d;
    int off0 = 0, off1 = 0, cnt = 0;
    for (int j = 0; j < d; ++j) {
        int o = row[j];
        if (o != 0) {
            int off = j * P1 + o;     // index into per-row polyval table
            if (cnt == 0) off0 = off; else off1 = off;
            ++cnt;                    // total order <= 2 -> cnt <= 2
        }
    }
    desc[b] = off0 | (off1 << 8);     // offset 0 -> pv==1 (order-0 Hermite)
}

__global__ __launch_bounds__(BLOCK) void pce_kernel(
    const float* __restrict__ x, const float* __restrict__ mean,
    const float* __restrict__ var, const float* __restrict__ basis,
    const int* __restrict__ desc, float* __restrict__ out, int n)
{
    __shared__ float s_pv[BN][DD * P1];   // per-row polyval table (150 floats)
    __shared__ int   s_desc[NBASIS];      // packed (off0 | off1<<8)
    const int tid  = threadIdx.x;
    const int row0 = blockIdx.x * BN;

    for (int i = tid; i < NBASIS; i += BLOCK) s_desc[i] = desc[i];

    // Hermite basis coefficients (broadcast loads, L1/L2 cached)
    float b00 = basis[0], b01 = basis[1], b02 = basis[2];
    float b10 = basis[3], b11 = basis[4], b12 = basis[5];
    float b20 = basis[6], b21 = basis[7], b22 = basis[8];

    for (int i = tid; i < BN * DD; i += BLOCK) {
        int r = i / DD, c = i - r * DD;
        int row = row0 + r;
        if (row < n) {
            float xv = (x[(size_t)row * DD + c] - mean[c]) / var[c];
            float x2 = xv * xv;
            s_pv[r][c * P1 + 0] = b00 + b01 * xv + b02 * x2;  // == 1.0
            s_pv[r][c * P1 + 1] = b10 + b11 * xv + b12 * x2;  // 2x
            s_pv[r][c * P1 + 2] = b20 + b21 * xv + b22 * x2;  // 4x^2 - 2
        }
    }
    __syncthreads();

    #pragma unroll
    for (int r = 0; r < BN; ++r) {
        int row = row0 + r;
        if (row >= n) break;
        const float* pvr = s_pv[r];
        float2* orow = (float2*)(out + (size_t)row * NBASIS);  // 5304 % 8 == 0: aligned
        for (int b2 = tid; b2 < NBASIS / 2; b2 += BLOCK) {     // 1326 even
            int d0 = s_desc[2 * b2];
            int d1 = s_desc[2 * b2 + 1];
            float2 v;
            v.x = pvr[d0 & 0xff] * pvr[(d0 >> 8) & 0xff];
            v.y = pvr[d1 & 0xff] * pvr[(d1 >> 8) & 0xff];
            orow[b2] = v;
        }
    }
}

extern "C" void kernel_launch(void* const* d_in, const int* in_sizes, int n_in,
                              void* d_out, int out_size, void* d_ws, size_t ws_size,
                              hipStream_t stream) {
    const float* x     = (const float*)d_in[0];
    const float* mean  = (const float*)d_in[1];
    const float* var   = (const float*)d_in[2];
    const float* basis = (const float*)d_in[3];
    const int*   idxset= (const int*)d_in[4];
    float* out = (float*)d_out;

    const int d      = in_sizes[1];          // 50
    const int n      = in_sizes[0] / d;      // 32768
    const int nbasis = in_sizes[4] / d;      // 1326

    int* desc = (int*)d_ws;                  // 1326 * 4 B scratch, rebuilt every call
    build_desc_kernel<<<(nbasis + BLOCK - 1) / BLOCK, BLOCK, 0, stream>>>(idxset, desc, nbasis, d);
    pce_kernel<<<(n + BN - 1) / BN, BLOCK, 0, stream>>>(x, mean, var, basis, desc, out, n);
}

// Round 2
// 199.109 us; speedup vs baseline: 1.0097x; 1.0097x over previous
//
#include <hip/hip_runtime.h>

// PCE basis expansion: Phi[n,b] = prod_j polyval(xn[n,j], idxset[b,j])
// D=50, P=2 -> each idxset row has <= 2 nonzero orders; polyval(_,0) == 1.
// Phi[n,b] = pv[off0]*pv[off1], off = dim*3+ord, packed off0|off1<<8.
// Output 32768x1326 fp32 = 174 MB -> write-BW bound (~28 us floor).
// R1: desc in REGISTERS (loaded once per thread, reused over 16 rows) and
// 16 rows/block fully unrolled -> 2 LDS gathers + 1 mul + 1 store per float,
// all chains independent (ILP-hidden latency). R0 was LDS-chain bound.

#define DD     50
#define P1     3
#define NBASIS 1326
#define NPAIR  (NBASIS / 2)   // 663
#define BN     16
#define BLOCK  256

// Kernel A: compress idxset rows into packed LDS-offset descriptors.
__global__ void build_desc_kernel(const int* __restrict__ idxset,
                                  int* __restrict__ desc, int nbasis, int d) {
    int b = blockIdx.x * blockDim.x + threadIdx.x;
    if (b >= nbasis) return;
    const int* row = idxset + (size_t)b * d;
    int off0 = 0, off1 = 0, cnt = 0;
    for (int j = 0; j < d; ++j) {
        int o = row[j];
        if (o != 0) {
            int off = j * P1 + o;     // index into per-row polyval table
            if (cnt == 0) off0 = off; else off1 = off;
            ++cnt;                    // total order <= 2 -> cnt <= 2
        }
    }
    desc[b] = off0 | (off1 << 8);     // offset 0 -> pv==1 (order-0 Hermite)
}

__global__ __launch_bounds__(BLOCK) void pce_kernel(
    const float* __restrict__ x, const float* __restrict__ mean,
    const float* __restrict__ var, const float* __restrict__ basis,
    const int* __restrict__ desc, float* __restrict__ out, int n)
{
    __shared__ float s_pv[BN][DD * P1 + 2];   // 16 x 152 floats = 9.7 KB
    const int tid  = threadIdx.x;
    const int row0 = blockIdx.x * BN;

    // Hermite basis coefficients (broadcast loads, cached)
    float b00 = basis[0], b01 = basis[1], b02 = basis[2];
    float b10 = basis[3], b11 = basis[4], b12 = basis[5];
    float b20 = basis[6], b21 = basis[7], b22 = basis[8];

    // Per-thread descriptors: 3 column-pair slots, loaded ONCE into registers.
    const int2* d2 = (const int2*)desc;
    const int p0 = tid, p1 = tid + BLOCK, p2 = tid + 2 * BLOCK;
    const bool has2 = (p2 < NPAIR);
    int2 dA = d2[p0];
    int2 dB = d2[p1];
    int2 dC = has2 ? d2[p2] : make_int2(0, 0);

    // Stage per-row polyval tables (coalesced x reads).
    for (int i = tid; i < BN * DD; i += BLOCK) {
        int r = i / DD, c = i - r * DD;
        float xv = (x[(size_t)(row0 + r) * DD + c] - mean[c]) / var[c];
        float x2 = xv * xv;
        s_pv[r][c * P1 + 0] = b00 + b01 * xv + b02 * x2;  // order 0 (== 1)
        s_pv[r][c * P1 + 1] = b10 + b11 * xv + b12 * x2;  // order 1
        s_pv[r][c * P1 + 2] = b20 + b21 * xv + b22 * x2;  // order 2
    }
    __syncthreads();

    #pragma unroll
    for (int r = 0; r < BN; ++r) {
        const float* pvr = s_pv[r];
        float2* orow = (float2*)(out + (size_t)(row0 + r) * NBASIS); // 5304%8==0
        float2 v;
        v.x = pvr[dA.x & 0xff] * pvr[dA.x >> 8];
        v.y = pvr[dA.y & 0xff] * pvr[dA.y >> 8];
        orow[p0] = v;
        v.x = pvr[dB.x & 0xff] * pvr[dB.x >> 8];
        v.y = pvr[dB.y & 0xff] * pvr[dB.y >> 8];
        orow[p1] = v;
        if (has2) {
            v.x = pvr[dC.x & 0xff] * pvr[dC.x >> 8];
            v.y = pvr[dC.y & 0xff] * pvr[dC.y >> 8];
            orow[p2] = v;
        }
    }
}

extern "C" void kernel_launch(void* const* d_in, const int* in_sizes, int n_in,
                              void* d_out, int out_size, void* d_ws, size_t ws_size,
                              hipStream_t stream) {
    const float* x     = (const float*)d_in[0];
    const float* mean  = (const float*)d_in[1];
    const float* var   = (const float*)d_in[2];
    const float* basis = (const float*)d_in[3];
    const int*   idxset= (const int*)d_in[4];
    float* out = (float*)d_out;

    const int d      = in_sizes[1];          // 50
    const int n      = in_sizes[0] / d;      // 32768
    const int nbasis = in_sizes[4] / d;      // 1326

    int* desc = (int*)d_ws;                  // 1326 * 4 B scratch, rebuilt every call
    build_desc_kernel<<<(nbasis + BLOCK - 1) / BLOCK, BLOCK, 0, stream>>>(idxset, desc, nbasis, d);
    pce_kernel<<<(n + BN - 1) / BN, BLOCK, 0, stream>>>(x, mean, var, basis, desc, out, n);
}